// Round 3
// baseline (148.919 us; speedup 1.0000x reference)
//
#include <hip/hip_runtime.h>

typedef unsigned short ushort_t;
typedef ushort_t u16x8 __attribute__((ext_vector_type(8)));
typedef __bf16 bf16x8 __attribute__((ext_vector_type(8)));
typedef float f32x4 __attribute__((ext_vector_type(4)));

#define DET 736
#define NPAD 768
#define NITER 23        // DET / 32
#define LDSTR 40        // padded LDS row stride (elems, 80 B): quad reads span all 8
                        // bank-groups -> 2-way aliasing (free) instead of 8-way

__device__ __forceinline__ ushort_t f2bf(float f) {
    unsigned u = __builtin_bit_cast(unsigned, f);
    u += 0x7FFFu + ((u >> 16) & 1u);
    return (ushort_t)(u >> 16);
}

// Bt[n][k] = cosw[k] * f[k - n + 735]; rows n>=736 zero.  (W symmetric.)
__global__ void prep_bt(const float* __restrict__ filt, ushort_t* __restrict__ Bt) {
    int idx = blockIdx.x * blockDim.x + threadIdx.x;
    if (idx >= NPAD * DET) return;
    int n = idx / DET;
    int k = idx - n * DET;
    float w = 0.05f * cosf(((float)k - 367.5f) * 0.001f);
    float v = (n < DET) ? w * filt[k - n + (DET - 1)] : 0.0f;  // index in [0,1471) always
    Bt[idx] = f2bf(v);
}

// OUT[M x 736] = cast_bf16(sino)[M x 736] * W'[736 x 736]
// 128x128 tile, BK=32, vector-load staging with fused fp32->bf16 cast,
// double-buffered LDS (1 barrier/iter), padded LDS stride.
__global__ __launch_bounds__(256) void gemm_fused(
    const float* __restrict__ A,      // M x DET fp32 sinogram
    const ushort_t* __restrict__ Bt,  // NPAD x DET bf16 bits
    float* __restrict__ C, int M)
{
    __shared__ ushort_t As[2][128 * LDSTR];
    __shared__ ushort_t Bs[2][128 * LDSTR];

    const int tid  = threadIdx.x;
    const int lane = tid & 63;
    const int warp = tid >> 6;   // 0..3
    const int wm   = warp & 1;   // 2x2 wave grid
    const int wn   = warp >> 1;
    const int quad = lane >> 4;  // 0..3
    const int l16  = lane & 15;

    const size_t row_a0 = (size_t)blockIdx.x * 128;
    const size_t row_b0 = (size_t)blockIdx.y * 128;

    // staging map: thread -> (row = tid>>1, k-half = (tid&1)*16); 16 k's per thread
    const int srow = tid >> 1;
    const int sh   = (tid & 1) * 16;
    const float*    ap = A  + (row_a0 + srow) * DET + sh;
    const ushort_t* bp = Bt + (row_b0 + srow) * DET + sh;
    const int soff = srow * LDSTR + sh;   // elem offset; byte = srow*80 + sh*2 (16B-aligned)

    f32x4 acc[4][4];
#pragma unroll
    for (int i = 0; i < 4; ++i)
#pragma unroll
        for (int jx = 0; jx < 4; ++jx)
            acc[i][jx] = (f32x4){0.f, 0.f, 0.f, 0.f};

    // ---- prologue: stage tile 0 into buffer 0 ----
    {
        f32x4 a0 = *(const f32x4*)(ap + 0);
        f32x4 a1 = *(const f32x4*)(ap + 4);
        f32x4 a2 = *(const f32x4*)(ap + 8);
        f32x4 a3 = *(const f32x4*)(ap + 12);
        u16x8 b0 = *(const u16x8*)(bp + 0);
        u16x8 b1 = *(const u16x8*)(bp + 8);
        bf16x8 c0 = {(__bf16)a0[0], (__bf16)a0[1], (__bf16)a0[2], (__bf16)a0[3],
                     (__bf16)a1[0], (__bf16)a1[1], (__bf16)a1[2], (__bf16)a1[3]};
        bf16x8 c1 = {(__bf16)a2[0], (__bf16)a2[1], (__bf16)a2[2], (__bf16)a2[3],
                     (__bf16)a3[0], (__bf16)a3[1], (__bf16)a3[2], (__bf16)a3[3]};
        *(u16x8*)(&As[0][soff])     = __builtin_bit_cast(u16x8, c0);
        *(u16x8*)(&As[0][soff + 8]) = __builtin_bit_cast(u16x8, c1);
        *(u16x8*)(&Bs[0][soff])     = b0;
        *(u16x8*)(&Bs[0][soff + 8]) = b1;
    }
    __syncthreads();

    for (int it = 0; it < NITER; ++it) {
        const int cur = it & 1;
        const int nxt = cur ^ 1;
        const int k1 = (it + 1) * 32;
        const bool pf = (it + 1 < NITER);   // wave-uniform

        // prefetch next tile into registers (latency hidden under MFMA block)
        f32x4 a0, a1, a2, a3; u16x8 b0, b1;
        if (pf) {
            a0 = *(const f32x4*)(ap + k1);
            a1 = *(const f32x4*)(ap + k1 + 4);
            a2 = *(const f32x4*)(ap + k1 + 8);
            a3 = *(const f32x4*)(ap + k1 + 12);
            b0 = *(const u16x8*)(bp + k1);
            b1 = *(const u16x8*)(bp + k1 + 8);
        }

        // fragments from current buffer
        u16x8 af[4], bfr[4];
#pragma unroll
        for (int mi = 0; mi < 4; ++mi)
            af[mi] = *(const u16x8*)(&As[cur][(wm * 64 + mi * 16 + l16) * LDSTR + quad * 8]);
#pragma unroll
        for (int ni = 0; ni < 4; ++ni)
            bfr[ni] = *(const u16x8*)(&Bs[cur][(wn * 64 + ni * 16 + l16) * LDSTR + quad * 8]);

#pragma unroll
        for (int mi = 0; mi < 4; ++mi)
#pragma unroll
            for (int ni = 0; ni < 4; ++ni)
                acc[mi][ni] = __builtin_amdgcn_mfma_f32_16x16x32_bf16(
                    __builtin_bit_cast(bf16x8, af[mi]),
                    __builtin_bit_cast(bf16x8, bfr[ni]),
                    acc[mi][ni], 0, 0, 0);

        // deposit prefetched tile into the other buffer
        if (pf) {
            bf16x8 c0 = {(__bf16)a0[0], (__bf16)a0[1], (__bf16)a0[2], (__bf16)a0[3],
                         (__bf16)a1[0], (__bf16)a1[1], (__bf16)a1[2], (__bf16)a1[3]};
            bf16x8 c1 = {(__bf16)a2[0], (__bf16)a2[1], (__bf16)a2[2], (__bf16)a2[3],
                         (__bf16)a3[0], (__bf16)a3[1], (__bf16)a3[2], (__bf16)a3[3]};
            *(u16x8*)(&As[nxt][soff])     = __builtin_bit_cast(u16x8, c0);
            *(u16x8*)(&As[nxt][soff + 8]) = __builtin_bit_cast(u16x8, c1);
            *(u16x8*)(&Bs[nxt][soff])     = b0;
            *(u16x8*)(&Bs[nxt][soff + 8]) = b1;
        }
        __syncthreads();
    }

    // epilogue: C/D layout col=lane&15, row=quad*4+reg [verified mapping]
#pragma unroll
    for (int mi = 0; mi < 4; ++mi) {
#pragma unroll
        for (int ni = 0; ni < 4; ++ni) {
            int colg = (int)row_b0 + wn * 64 + ni * 16 + l16;
            if (colg < DET) {
#pragma unroll
                for (int r = 0; r < 4; ++r) {
                    size_t rowg = row_a0 + wm * 64 + mi * 16 + quad * 4 + r;
                    C[rowg * DET + colg] = acc[mi][ni][r];
                }
            }
        }
    }
}

extern "C" void kernel_launch(void* const* d_in, const int* in_sizes, int n_in,
                              void* d_out, int out_size, void* d_ws, size_t ws_size,
                              hipStream_t stream) {
    const float* sino = (const float*)d_in[0];
    const float* filt = (const float*)d_in[1];
    int total = in_sizes[0];     // 16*1*1152*736 = 13,565,952
    int M = total / DET;         // 18432

    ushort_t* Btb = (ushort_t*)d_ws;
    float* out = (float*)d_out;

    prep_bt<<<(NPAD * DET) / 256, 256, 0, stream>>>(filt, Btb);

    dim3 grid(M / 128, NPAD / 128);  // 144 x 6
    gemm_fused<<<grid, 256, 0, stream>>>(sino, Btb, out, M);
}

// Round 4
// 145.077 us; speedup vs baseline: 1.0265x; 1.0265x over previous
//
#include <hip/hip_runtime.h>

typedef unsigned short ushort_t;
typedef ushort_t u16x8 __attribute__((ext_vector_type(8)));
typedef __bf16 bf16x8 __attribute__((ext_vector_type(8)));
typedef float f32x4 __attribute__((ext_vector_type(4)));

#define DET 736
#define NPAD 768
#define NITER 23   // DET / 32

__device__ __forceinline__ ushort_t f2bf(float f) {
    unsigned u = __builtin_bit_cast(unsigned, f);
    u += 0x7FFFu + ((u >> 16) & 1u);
    return (ushort_t)(u >> 16);
}

// pure fp32 -> bf16 cast, 8 elements/thread (cos weight folded into Bt)
__global__ void cast_x(const float* __restrict__ in, ushort_t* __restrict__ out, int total) {
    int idx = (blockIdx.x * blockDim.x + threadIdx.x) * 8;
    if (idx >= total) return;
    float4 a = *(const float4*)(in + idx);
    float4 b = *(const float4*)(in + idx + 4);
    u16x8 o;
    o[0] = f2bf(a.x); o[1] = f2bf(a.y); o[2] = f2bf(a.z); o[3] = f2bf(a.w);
    o[4] = f2bf(b.x); o[5] = f2bf(b.y); o[6] = f2bf(b.z); o[7] = f2bf(b.w);
    *(u16x8*)(out + idx) = o;
}

// Bt[n][k] = cosw[k] * f[k - n + 735]; rows n>=736 zero.  (W symmetric.)
__global__ void prep_bt(const float* __restrict__ filt, ushort_t* __restrict__ Bt) {
    int idx = blockIdx.x * blockDim.x + threadIdx.x;
    if (idx >= NPAD * DET) return;
    int n = idx / DET;
    int k = idx - n * DET;
    float w = 0.05f * cosf(((float)k - 367.5f) * 0.001f);
    float v = (n < DET) ? w * filt[k - n + (DET - 1)] : 0.0f;  // index in [0,1471) always
    Bt[idx] = f2bf(v);
}

// OUT[M x 736] = X[M x 736] * W'[736 x 736], bf16 MFMA.
// 128x64 tile (1728 blocks -> ~27 waves/CU ceiling, 2x R1), BK=32,
// vector staging (bf16), stride-32 LDS (R1 conflict profile),
// loads hoisted above first barrier for cross-iter overlap.
__global__ __launch_bounds__(256, 6) void gemm_bt(
    const ushort_t* __restrict__ A,   // M x DET bf16 bits
    const ushort_t* __restrict__ Bt,  // NPAD x DET bf16 bits
    float* __restrict__ C, int M)
{
    __shared__ ushort_t As[128 * 32];  // 8 KB
    __shared__ ushort_t Bs[64 * 32];   // 4 KB

    const int tid  = threadIdx.x;
    const int lane = tid & 63;
    const int warp = tid >> 6;   // 0..3
    const int wm   = warp & 1;   // rows: wm*64
    const int wn   = warp >> 1;  // cols: wn*32
    const int quad = lane >> 4;  // 0..3
    const int l16  = lane & 15;

    const size_t row_a0 = (size_t)blockIdx.x * 128;
    const size_t row_b0 = (size_t)blockIdx.y * 64;

    // staging: A-tile 128x32 = 512 x 16B chunks (2/thread), B-tile 64x32 = 256 (1/thread)
    const int ca0 = tid, ca1 = tid + 256;
    const int ra0 = ca0 >> 2, qa0 = ca0 & 3;
    const int ra1 = ca1 >> 2, qa1 = ca1 & 3;
    const int rb  = tid >> 2, qb  = tid & 3;

    const ushort_t* a0p = A  + (row_a0 + ra0) * DET + qa0 * 8;
    const ushort_t* a1p = A  + (row_a0 + ra1) * DET + qa1 * 8;
    const ushort_t* b0p = Bt + (row_b0 + rb)  * DET + qb  * 8;

    f32x4 acc[4][2];
#pragma unroll
    for (int i = 0; i < 4; ++i)
#pragma unroll
        for (int jx = 0; jx < 2; ++jx)
            acc[i][jx] = (f32x4){0.f, 0.f, 0.f, 0.f};

    for (int it = 0; it < NITER; ++it) {
        const int k0 = it * 32;
        // global loads first: overlap previous iter's MFMA + barrier wait
        u16x8 a0 = *(const u16x8*)(a0p + k0);
        u16x8 a1 = *(const u16x8*)(a1p + k0);
        u16x8 b0 = *(const u16x8*)(b0p + k0);
        if (it) __syncthreads();           // prior iter's ds_reads complete
        *(u16x8*)(As + ca0 * 8) = a0;
        *(u16x8*)(As + ca1 * 8) = a1;
        *(u16x8*)(Bs + tid * 8) = b0;
        __syncthreads();                   // tile visible

        u16x8 af[4], bfr[2];
#pragma unroll
        for (int mi = 0; mi < 4; ++mi)
            af[mi] = *(const u16x8*)(As + (wm * 64 + mi * 16 + l16) * 32 + quad * 8);
#pragma unroll
        for (int ni = 0; ni < 2; ++ni)
            bfr[ni] = *(const u16x8*)(Bs + (wn * 32 + ni * 16 + l16) * 32 + quad * 8);
#pragma unroll
        for (int mi = 0; mi < 4; ++mi)
#pragma unroll
            for (int ni = 0; ni < 2; ++ni)
                acc[mi][ni] = __builtin_amdgcn_mfma_f32_16x16x32_bf16(
                    __builtin_bit_cast(bf16x8, af[mi]),
                    __builtin_bit_cast(bf16x8, bfr[ni]),
                    acc[mi][ni], 0, 0, 0);
    }

    // epilogue: C/D layout col=lane&15, row=quad*4+reg [verified mapping]
#pragma unroll
    for (int mi = 0; mi < 4; ++mi) {
#pragma unroll
        for (int ni = 0; ni < 2; ++ni) {
            int colg = (int)row_b0 + wn * 32 + ni * 16 + l16;
            if (colg < DET) {
#pragma unroll
                for (int r = 0; r < 4; ++r) {
                    size_t rowg = row_a0 + wm * 64 + mi * 16 + quad * 4 + r;
                    C[rowg * DET + colg] = acc[mi][ni][r];
                }
            }
        }
    }
}

extern "C" void kernel_launch(void* const* d_in, const int* in_sizes, int n_in,
                              void* d_out, int out_size, void* d_ws, size_t ws_size,
                              hipStream_t stream) {
    const float* sino = (const float*)d_in[0];
    const float* filt = (const float*)d_in[1];
    int total = in_sizes[0];     // 16*1*1152*736 = 13,565,952
    int M = total / DET;         // 18432

    ushort_t* Xbf = (ushort_t*)d_ws;
    ushort_t* Btb = Xbf + (size_t)total;   // 27.1MB offset, 16B-aligned
    float* out = (float*)d_out;

    cast_x<<<(total / 8 + 255) / 256, 256, 0, stream>>>(sino, Xbf, total);
    prep_bt<<<(NPAD * DET) / 256, 256, 0, stream>>>(filt, Btb);

    dim3 grid(M / 128, NPAD / 64);  // 144 x 12 = 1728 blocks
    gemm_bt<<<grid, 256, 0, stream>>>(Xbf, Btb, out, M);
}

// Round 5
// 143.985 us; speedup vs baseline: 1.0343x; 1.0076x over previous
//
#include <hip/hip_runtime.h>

typedef unsigned short ushort_t;
typedef ushort_t u16x8 __attribute__((ext_vector_type(8)));
typedef __bf16 bf16x8 __attribute__((ext_vector_type(8)));
typedef float f32x4 __attribute__((ext_vector_type(4)));

#define DET 736
#define NPAD 768
#define NKB 23    // K-blocks of 32
#define NBY 12    // 64-col tiles

__device__ __forceinline__ ushort_t f2bf(float f) {
    unsigned u = __builtin_bit_cast(unsigned, f);
    u += 0x7FFFu + ((u >> 16) & 1u);
    return (ushort_t)(u >> 16);
}

// fp32 -> bf16 cast + swizzle into MFMA A-fragment order.
// chunk t = (rs*23 + kb)*64 + l  ->  lane l of frag (rs,kb):
//   row = rs*16 + (l&15), k = kb*32 + ((l>>4))*8 + j, j=0..7
__global__ void cast_swz_a(const float* __restrict__ in, ushort_t* __restrict__ out) {
    int t = blockIdx.x * 256 + threadIdx.x;      // < 1152*23*64 = 1,695,744
    int l  = t & 63;
    int fi = t >> 6;
    int kb = fi % NKB;
    int rs = fi / NKB;
    int row = rs * 16 + (l & 15);
    int k0  = kb * 32 + (l >> 4) * 8;
    const float* p = in + row * DET + k0;
    float4 a = *(const float4*)p;
    float4 b = *(const float4*)(p + 4);
    u16x8 o;
    o[0] = f2bf(a.x); o[1] = f2bf(a.y); o[2] = f2bf(a.z); o[3] = f2bf(a.w);
    o[4] = f2bf(b.x); o[5] = f2bf(b.y); o[6] = f2bf(b.z); o[7] = f2bf(b.w);
    *(u16x8*)(out + (size_t)t * 8) = o;
}

// W'[col][k] = cosw[k]*f[k-col+735] in B-fragment order, per 64-col panel:
// chunk G = ((by*23 + kb)*4 + ns)*64 + l -> col = by*64+ns*16+(l&15), k = kb*32+(l>>4)*8+j
__global__ void prep_bt_swz(const float* __restrict__ filt, ushort_t* __restrict__ B) {
    int G = blockIdx.x * 256 + threadIdx.x;      // < 12*23*4*64 = 70656
    int l  = G & 63;
    int ns = (G >> 6) & 3;
    int kb = (G >> 8) % NKB;
    int by = (G >> 8) / NKB;
    int col = by * 64 + ns * 16 + (l & 15);
    int k0  = kb * 32 + (l >> 4) * 8;
    u16x8 o;
#pragma unroll
    for (int j = 0; j < 8; ++j) {
        int k = k0 + j;
        float w = 0.05f * cosf(((float)k - 367.5f) * 0.001f);
        float v = (col < DET) ? w * filt[k - col + (DET - 1)] : 0.0f;  // idx in [0,1471)
        o[j] = f2bf(v);
    }
    *(u16x8*)(B + (size_t)G * 8) = o;
}

// Barrier-free K-loop GEMM: A-frags streamed global->VGPR (pre-swizzled),
// B K-panel staged to LDS in 2 phases (4 barriers total), conflict-free
// lane-sequential ds_read_b128. Tile 256x64, 4 waves x 64 rows, 16x16x32 MFMA.
__global__ __launch_bounds__(256, 3) void gemm_nb(
    const ushort_t* __restrict__ A,   // swizzled frags, 1152*23*64*8 elems
    const ushort_t* __restrict__ B,   // swizzled panels, 12*23*4*64*8 elems
    float* __restrict__ C)
{
    __shared__ ushort_t Bs[12 * 256 * 8];   // 49152 B: 12 kb x 4 ns x 64 lanes x 16B

    const int tid  = threadIdx.x;
    const int lane = tid & 63;
    const int w    = tid >> 6;    // 0..3, owns rows w*64..+63
    const int quad = lane >> 4;
    const int l16  = lane & 15;
    const int bx = blockIdx.x, by = blockIdx.y;

    // A frag base: strips rs = bx*16 + w*4 + mi; chunk ((rs*23+kb)*64+lane)
    const ushort_t* pA = A + ((size_t)(bx * 16 + w * 4) * NKB * 64 + lane) * 8;
    const ushort_t* pB = B + (size_t)by * (NKB * 256) * 8;

    f32x4 acc[4][4];
#pragma unroll
    for (int i = 0; i < 4; ++i)
#pragma unroll
        for (int j = 0; j < 4; ++j)
            acc[i][j] = (f32x4){0.f, 0.f, 0.f, 0.f};

#define STAGE(CHUNKS, OFF)                                            \
    for (int c = tid; c < (CHUNKS); c += 256)                         \
        *(u16x8*)(Bs + (size_t)c * 8) = *(const u16x8*)(pB + ((size_t)(OFF) + c) * 8);

#define BODY(KB, KB0)                                                          \
    {                                                                          \
        u16x8 af[4], bf[4];                                                    \
        _Pragma("unroll")                                                      \
        for (int mi = 0; mi < 4; ++mi)                                         \
            af[mi] = *(const u16x8*)(pA + ((size_t)mi * NKB * 64 + (KB) * 64) * 8); \
        _Pragma("unroll")                                                      \
        for (int ni = 0; ni < 4; ++ni)                                         \
            bf[ni] = *(const u16x8*)(Bs + (((KB) - (KB0)) * 256 + ni * 64 + lane) * 8); \
        _Pragma("unroll")                                                      \
        for (int mi = 0; mi < 4; ++mi)                                         \
            _Pragma("unroll")                                                  \
            for (int ni = 0; ni < 4; ++ni)                                     \
                acc[mi][ni] = __builtin_amdgcn_mfma_f32_16x16x32_bf16(         \
                    __builtin_bit_cast(bf16x8, af[mi]),                        \
                    __builtin_bit_cast(bf16x8, bf[ni]),                        \
                    acc[mi][ni], 0, 0, 0);                                     \
    }

    // phase 0: kb 0..11
    STAGE(12 * 256, 0)
    __syncthreads();
#pragma unroll
    for (int kb = 0; kb < 12; ++kb) BODY(kb, 0)
    __syncthreads();
    // phase 1: kb 12..22
    STAGE(11 * 256, 12 * 256)
    __syncthreads();
#pragma unroll
    for (int kb = 12; kb < 23; ++kb) BODY(kb, 12)

    // epilogue: C/D layout col=lane&15, row=quad*4+reg [verified R1]
#pragma unroll
    for (int mi = 0; mi < 4; ++mi) {
#pragma unroll
        for (int ni = 0; ni < 4; ++ni) {
            int colg = by * 64 + ni * 16 + l16;
            if (colg < DET) {
#pragma unroll
                for (int r = 0; r < 4; ++r) {
                    size_t rowg = (size_t)bx * 256 + w * 64 + mi * 16 + quad * 4 + r;
                    C[rowg * DET + colg] = acc[mi][ni][r];
                }
            }
        }
    }
#undef STAGE
#undef BODY
}

extern "C" void kernel_launch(void* const* d_in, const int* in_sizes, int n_in,
                              void* d_out, int out_size, void* d_ws, size_t ws_size,
                              hipStream_t stream) {
    const float* sino = (const float*)d_in[0];
    const float* filt = (const float*)d_in[1];
    int total = in_sizes[0];     // 16*1*1152*736 = 13,565,952

    ushort_t* Aswz = (ushort_t*)d_ws;               // 27.13 MB
    ushort_t* Bswz = Aswz + (size_t)total;          // +1.13 MB
    float* out = (float*)d_out;

    cast_swz_a<<<total / 8 / 256, 256, 0, stream>>>(sino, Aswz);        // 6624 blocks
    prep_bt_swz<<<(NBY * NKB * 4 * 64) / 256, 256, 0, stream>>>(filt, Bswz); // 276 blocks

    dim3 grid(18432 / 256, NBY);   // 72 x 12 = 864
    gemm_nb<<<grid, 256, 0, stream>>>(Aswz, Bswz, out);
}

// Round 6
// 142.369 us; speedup vs baseline: 1.0460x; 1.0114x over previous
//
#include <hip/hip_runtime.h>

typedef unsigned short ushort_t;
typedef ushort_t u16x8 __attribute__((ext_vector_type(8)));
typedef __bf16 bf16x8 __attribute__((ext_vector_type(8)));
typedef float f32x4 __attribute__((ext_vector_type(4)));

#define DET 736
#define NKB 23    // K-blocks of 32
#define NPAN 12   // 64-col output panels (768 padded cols)

__device__ __forceinline__ ushort_t f2bf(float f) {
    unsigned u = __builtin_bit_cast(unsigned, f);
    u += 0x7FFFu + ((u >> 16) & 1u);
    return (ushort_t)(u >> 16);
}

// W'[col][k] = cosw[k]*f[k-col+735] in B-fragment order, per 64-col panel:
// chunk G = ((by*23 + kb)*4 + ns)*64 + l -> col = by*64+ns*16+(l&15), k = kb*32+(l>>4)*8+j
__global__ void prep_bt_swz(const float* __restrict__ filt, ushort_t* __restrict__ B) {
    int G = blockIdx.x * 256 + threadIdx.x;      // < 12*23*4*64 = 70656
    int l  = G & 63;
    int ns = (G >> 6) & 3;
    int kb = (G >> 8) % NKB;
    int by = (G >> 8) / NKB;
    int col = by * 64 + ns * 16 + (l & 15);
    int k0  = kb * 32 + (l >> 4) * 8;
    u16x8 o;
#pragma unroll
    for (int j = 0; j < 8; ++j) {
        int k = k0 + j;
        float w = 0.05f * cosf(((float)k - 367.5f) * 0.001f);
        float v = (col < DET) ? w * filt[k - col + (DET - 1)] : 0.0f;  // idx in [0,1471)
        o[j] = f2bf(v);
    }
    *(u16x8*)(B + (size_t)G * 8) = o;
}

// Single-pass-A GEMM: block = 32 rows x ALL 768 cols.
// A panel (32 x 736) staged fp32->bf16 into LDS in fragment order, read ONCE
// from HBM (fused cast, no cast pass, no A re-reads through L3).
// B streamed global->VGPR from pre-swizzled L2-resident panels.
// One barrier per block; zero-conflict lane-sequential LDS; 3 blocks/CU.
__global__ __launch_bounds__(256, 3) void gemm_f(
    const float* __restrict__ A,      // M x DET fp32 sinogram
    const ushort_t* __restrict__ B,   // swizzled panels, 12*23*4*64*8 elems
    float* __restrict__ C)
{
    __shared__ ushort_t As[2944 * 8];   // 2 strips x 23 kb x 64 lanes x 16B = 47104 B

    const int tid  = threadIdx.x;
    const int lane = tid & 63;
    const int w    = tid >> 6;    // wave 0..3: owns 64-col panel (cg*4 + w) per cg
    const int quad = lane >> 4;
    const int l16  = lane & 15;
    const size_t r0 = (size_t)blockIdx.x * 32;

    // ---- stage A: rows r0..r0+31, full K, fragment order ----
    // chunk c = (rs*23 + kb)*64 + l  ->  row = rs*16+(l&15), k = kb*32+(l>>4)*8+j
    for (int c = tid; c < 2944; c += 256) {
        int l  = c & 63;
        int t  = c >> 6;
        int kb = t % NKB;
        int rs = t / NKB;
        int row = rs * 16 + (l & 15);
        int k0  = kb * 32 + (l >> 4) * 8;
        const float* p = A + (r0 + row) * DET + k0;
        float4 x = *(const float4*)p;
        float4 y = *(const float4*)(p + 4);
        u16x8 o;
        o[0] = f2bf(x.x); o[1] = f2bf(x.y); o[2] = f2bf(x.z); o[3] = f2bf(x.w);
        o[4] = f2bf(y.x); o[5] = f2bf(y.y); o[6] = f2bf(y.z); o[7] = f2bf(y.w);
        *(u16x8*)(As + (size_t)c * 8) = o;
    }
    __syncthreads();   // the only barrier

    f32x4 acc[3][2][4];
#pragma unroll
    for (int cg = 0; cg < 3; ++cg)
#pragma unroll
        for (int mi = 0; mi < 2; ++mi)
#pragma unroll
            for (int ni = 0; ni < 4; ++ni)
                acc[cg][mi][ni] = (f32x4){0.f, 0.f, 0.f, 0.f};

    for (int kb = 0; kb < NKB; ++kb) {
        u16x8 af[2];
#pragma unroll
        for (int mi = 0; mi < 2; ++mi)
            af[mi] = *(const u16x8*)(As + ((size_t)(mi * NKB + kb) * 64 + lane) * 8);
#pragma unroll
        for (int cg = 0; cg < 3; ++cg) {
            const ushort_t* pB = B + ((size_t)((cg * 4 + w) * NKB + kb) * 4 * 64 + lane) * 8;
#pragma unroll
            for (int ni = 0; ni < 4; ++ni) {
                u16x8 bfv = *(const u16x8*)(pB + (size_t)ni * 64 * 8);
#pragma unroll
                for (int mi = 0; mi < 2; ++mi)
                    acc[cg][mi][ni] = __builtin_amdgcn_mfma_f32_16x16x32_bf16(
                        __builtin_bit_cast(bf16x8, af[mi]),
                        __builtin_bit_cast(bf16x8, bfv),
                        acc[cg][mi][ni], 0, 0, 0);
            }
        }
    }

    // epilogue: C/D layout col=lane&15, row=quad*4+reg [verified mapping]
#pragma unroll
    for (int cg = 0; cg < 3; ++cg) {
#pragma unroll
        for (int ni = 0; ni < 4; ++ni) {
            int colg = (cg * 4 + w) * 64 + ni * 16 + l16;
            if (colg < DET) {
#pragma unroll
                for (int mi = 0; mi < 2; ++mi)
#pragma unroll
                    for (int r = 0; r < 4; ++r) {
                        size_t rowg = r0 + mi * 16 + quad * 4 + r;
                        C[rowg * DET + colg] = acc[cg][mi][ni][r];
                    }
            }
        }
    }
}

extern "C" void kernel_launch(void* const* d_in, const int* in_sizes, int n_in,
                              void* d_out, int out_size, void* d_ws, size_t ws_size,
                              hipStream_t stream) {
    const float* sino = (const float*)d_in[0];
    const float* filt = (const float*)d_in[1];
    int total = in_sizes[0];     // 16*1*1152*736 = 13,565,952
    int M = total / DET;         // 18432

    ushort_t* Bswz = (ushort_t*)d_ws;   // 1.13 MB
    float* out = (float*)d_out;

    prep_bt_swz<<<(NPAN * NKB * 4 * 64) / 256, 256, 0, stream>>>(filt, Bswz); // 276 blocks

    gemm_f<<<M / 32, 256, 0, stream>>>(sino, Bswz, out);   // 576 blocks
}